// Round 1
// baseline (2950.429 us; speedup 1.0000x reference)
//
#include <hip/hip_runtime.h>

constexpr int B = 4, T = 8, N = 4096, C0 = 64, C1 = 128;
constexpr int M = 1024, KNN = 32;

// ---------------- transpose features (B,T,64,4096) -> featT (B,T,4096,64) ----
__global__ __launch_bounds__(256) void transpose_kernel(const float* __restrict__ f,
                                                        float* __restrict__ ft) {
  __shared__ float tile[64][65];
  int bt = blockIdx.y;                 // 0..31
  int n0 = blockIdx.x * 64;            // n chunk
  const float* src = f + (size_t)bt * C0 * N;
  int tx = threadIdx.x & 63, ty = threadIdx.x >> 6;  // 256 threads
  for (int r = ty; r < 64; r += 4)
    tile[r][tx] = src[(size_t)r * N + n0 + tx];
  __syncthreads();
  float* dst = ft + ((size_t)bt * N + n0) * 64;
  for (int r = ty; r < 64; r += 4)
    dst[(size_t)r * 64 + tx] = tile[tx][r];
}

// ---------------- furthest point sampling: one block per (b,t) --------------
__global__ __launch_bounds__(1024) void fps_kernel(const float* __restrict__ xyz,
                                                   float* __restrict__ out_xyz) {
  __shared__ float xs[N], ys[N], zs[N];
  __shared__ float rv[16];
  __shared__ int ri[16];
  __shared__ int lidx;
  int bt = blockIdx.x;
  const float* p = xyz + (size_t)bt * N * 3;
  int tid = threadIdx.x;
  for (int i = tid; i < N; i += 1024) {
    xs[i] = p[i * 3 + 0];
    ys[i] = p[i * 3 + 1];
    zs[i] = p[i * 3 + 2];
  }
  __syncthreads();
  float dist[4];
  dist[0] = dist[1] = dist[2] = dist[3] = 1e10f;
  if (tid == 0) {
    out_xyz[((size_t)bt * M) * 3 + 0] = xs[0];
    out_xyz[((size_t)bt * M) * 3 + 1] = ys[0];
    out_xyz[((size_t)bt * M) * 3 + 2] = zs[0];
    lidx = 0;
  }
  __syncthreads();
  int last = 0;
  for (int s = 1; s < M; ++s) {
    float lx = xs[last], ly = ys[last], lz = zs[last];
    float bv = -1.0f;
    int bi = 0x7fffffff;
#pragma unroll
    for (int j = 0; j < 4; ++j) {
      int pidx = j * 1024 + tid;
      float dx = __fsub_rn(xs[pidx], lx);
      float dy = __fsub_rn(ys[pidx], ly);
      float dz = __fsub_rn(zs[pidx], lz);
      float d = __fadd_rn(__fadd_rn(__fmul_rn(dx, dx), __fmul_rn(dy, dy)), __fmul_rn(dz, dz));
      float nd = fminf(dist[j], d);
      dist[j] = nd;
      // j ascending => pidx ascending; strict > keeps earliest index
      if (nd > bv) { bv = nd; bi = pidx; }
    }
    // wave-level reduce with first-occurrence tie-break (smaller index wins)
#pragma unroll
    for (int off = 1; off < 64; off <<= 1) {
      float ov = __shfl_xor(bv, off, 64);
      int oi = __shfl_xor(bi, off, 64);
      if (ov > bv || (ov == bv && oi < bi)) { bv = ov; bi = oi; }
    }
    int w = tid >> 6;
    if ((tid & 63) == 0) { rv[w] = bv; ri[w] = bi; }
    __syncthreads();
    if (tid < 64) {
      float fv = -1.0f;
      int fi = 0x7fffffff;
      if (tid < 16) { fv = rv[tid]; fi = ri[tid]; }
#pragma unroll
      for (int off = 1; off < 16; off <<= 1) {
        float ov = __shfl_xor(fv, off, 64);
        int oi = __shfl_xor(fi, off, 64);
        if (ov > fv || (ov == fv && oi < fi)) { fv = ov; fi = oi; }
      }
      if (tid == 0) {
        lidx = fi;
        out_xyz[((size_t)(bt * M + s)) * 3 + 0] = xs[fi];
        out_xyz[((size_t)(bt * M + s)) * 3 + 1] = ys[fi];
        out_xyz[((size_t)(bt * M + s)) * 3 + 2] = zs[fi];
      }
    }
    __syncthreads();
    last = lidx;
  }
}

// ---------------- ball query: one wave per (b,t,di,m) -----------------------
__global__ __launch_bounds__(256) void ballq_kernel(const float* __restrict__ xyz,
                                                    const float* __restrict__ anchors,
                                                    int* __restrict__ idxbuf) {
  const float R2 = 0.04f;
  int w = threadIdx.x >> 6, lane = threadIdx.x & 63;
  int q = blockIdx.x * 4 + w;  // 0..98303  q = (bt*3 + di)*M + m
  int m = q & (M - 1);
  int di = (q >> 10) % 3;
  int bt = q / (M * 3);
  int b = bt >> 3, t = bt & 7;
  int srct = t + di - 1;
  srct = srct < 0 ? 0 : (srct > 7 ? 7 : srct);
  const float* anc = anchors + ((size_t)(bt * M + m)) * 3;
  float ax = anc[0], ay = anc[1], az = anc[2];
  const float* pts = xyz + ((size_t)(b * T + srct)) * N * 3;
  int* outp = idxbuf + (size_t)q * KNN;
  int cnt = 0, first = 0;
  for (int c = 0; c < N / 64 && cnt < KNN; ++c) {
    int pi = c * 64 + lane;
    const float* pp = pts + (size_t)pi * 3;
    float dx = __fsub_rn(ax, pp[0]);
    float dy = __fsub_rn(ay, pp[1]);
    float dz = __fsub_rn(az, pp[2]);
    float d2 = __fadd_rn(__fadd_rn(__fmul_rn(dx, dx), __fmul_rn(dy, dy)), __fmul_rn(dz, dz));
    bool hit = d2 < R2;
    unsigned long long mask = __ballot(hit);
    if (cnt == 0 && mask) first = c * 64 + (int)__builtin_ctzll(mask);
    int prefix = (int)__popcll(mask & ((1ull << lane) - 1ull));
    int slot = cnt + prefix;
    if (hit && slot < KNN) outp[slot] = pi;
    cnt += (int)__popcll(mask);
  }
  int cntK = cnt < KNN ? cnt : KNN;
  int fill = (cnt == 0) ? 0 : first;
  if (lane < KNN && lane >= cntK) outp[lane] = fill;
}

// ---------------- fused grouping + 2-layer MLP + maxpool + temporal sum -----
__global__ __launch_bounds__(256) void mlp_kernel(const float* __restrict__ xyz,
                                                  const float* __restrict__ featT,
                                                  const float* __restrict__ Wd,
                                                  const float* __restrict__ Wf,
                                                  const float* __restrict__ W1,
                                                  const float* __restrict__ anchors,
                                                  const int* __restrict__ idxbuf,
                                                  float* __restrict__ out_feats) {
  __shared__ __align__(16) float hbuf[4][64];
  __shared__ __align__(16) float fstage[4][128];
  int w = threadIdx.x >> 6, lane = threadIdx.x & 63;
  int bt = blockIdx.x >> 8;            // 8192 blocks
  int m0 = (blockIdx.x & 255) * 4;
  int m = m0 + w;
  int b = bt >> 3, t = bt & 7;
  // per-lane weight rows in registers
  float wf[64], w1a[64], w1b[64];
#pragma unroll
  for (int c = 0; c < 64; c += 4) {
    *(float4*)&wf[c] = *(const float4*)&Wf[lane * 64 + c];
    *(float4*)&w1a[c] = *(const float4*)&W1[lane * 64 + c];
    *(float4*)&w1b[c] = *(const float4*)&W1[(lane + 64) * 64 + c];
  }
  float4 wd = *(const float4*)&Wd[lane * 4];
  int aoff = __builtin_amdgcn_readfirstlane(bt * M + m);
  float ax = anchors[(size_t)aoff * 3 + 0];
  float ay = anchors[(size_t)aoff * 3 + 1];
  float az = anchors[(size_t)aoff * 3 + 2];
  float a0 = 0.f, a1 = 0.f;
  for (int di = 0; di < 3; ++di) {
    int srct = t + di - 1;
    srct = srct < 0 ? 0 : (srct > 7 ? 7 : srct);
    const float* pts = xyz + ((size_t)(b * T + srct)) * N * 3;
    const float* ft = featT + ((size_t)(b * T + srct)) * N * 64;
    int ipoff = __builtin_amdgcn_readfirstlane(((bt * 3 + di) * M + m) * KNN);
    const int* ip = idxbuf + ipoff;
    float tval = (float)(di - 1);
    float mx0 = 0.f, mx1 = 0.f;
    for (int k = 0; k < KNN; ++k) {
      int n = __builtin_amdgcn_readfirstlane(ip[k]);
      const float* gp = ft + (size_t)n * 64;   // wave-uniform -> s_load
      const float* pp = pts + (size_t)n * 3;
      float px = pp[0], py = pp[1], pz = pp[2];
      float f0 = 0.f, f1 = 0.f, f2 = 0.f, f3 = 0.f;
#pragma unroll
      for (int c = 0; c < 64; c += 4) {
        f0 = fmaf(gp[c + 0], wf[c + 0], f0);
        f1 = fmaf(gp[c + 1], wf[c + 1], f1);
        f2 = fmaf(gp[c + 2], wf[c + 2], f2);
        f3 = fmaf(gp[c + 3], wf[c + 3], f3);
      }
      float ff = (f0 + f1) + (f2 + f3);
      float dd = fmaf(px - ax, wd.x, fmaf(py - ay, wd.y, fmaf(pz - az, wd.z, tval * wd.w)));
      float h = fmaxf(ff, 0.f) + fmaxf(dd, 0.f);
      hbuf[w][lane] = h;
      float o0a = 0.f, o0b = 0.f, o1a = 0.f, o1b = 0.f;
#pragma unroll
      for (int c = 0; c < 64; c += 4) {
        float4 hv = *(const float4*)&hbuf[w][c];
        o0a = fmaf(hv.x, w1a[c + 0], o0a); o1a = fmaf(hv.x, w1b[c + 0], o1a);
        o0b = fmaf(hv.y, w1a[c + 1], o0b); o1b = fmaf(hv.y, w1b[c + 1], o1b);
        o0a = fmaf(hv.z, w1a[c + 2], o0a); o1a = fmaf(hv.z, w1b[c + 2], o1a);
        o0b = fmaf(hv.w, w1a[c + 3], o0b); o1b = fmaf(hv.w, w1b[c + 3], o1b);
      }
      float o0 = o0a + o0b, o1 = o1a + o1b;
      mx0 = fmaxf(mx0, fmaxf(o0, 0.f));
      mx1 = fmaxf(mx1, fmaxf(o1, 0.f));
    }
    a0 += mx0;
    a1 += mx1;
  }
  fstage[w][lane] = a0;
  fstage[w][lane + 64] = a1;
  __syncthreads();
  if (threadIdx.x < 128) {
    int c1 = threadIdx.x;
    float4 v = make_float4(fstage[0][c1], fstage[1][c1], fstage[2][c1], fstage[3][c1]);
    *(float4*)&out_feats[((size_t)(bt * C1 + c1)) * M + m0] = v;
  }
}

extern "C" void kernel_launch(void* const* d_in, const int* in_sizes, int n_in,
                              void* d_out, int out_size, void* d_ws, size_t ws_size,
                              hipStream_t stream) {
  const float* xyzs = (const float*)d_in[0];
  const float* feats = (const float*)d_in[1];
  const float* Wd = (const float*)d_in[2];
  const float* Wf = (const float*)d_in[3];
  const float* W1 = (const float*)d_in[4];
  float* out_xyz = (float*)d_out;                           // (B,8,M,3)
  float* out_feats = (float*)d_out + (size_t)B * T * M * 3; // (B,8,C1,M)
  char* ws = (char*)d_ws;
  float* featT = (float*)ws;                                // B*T*N*64 f32 = 33.5MB
  int* idxbuf = (int*)(ws + (size_t)B * T * N * 64 * 4);    // B*T*3*M*K i32 = 12.6MB
  transpose_kernel<<<dim3(N / 64, B * T), 256, 0, stream>>>(feats, featT);
  fps_kernel<<<B * T, 1024, 0, stream>>>(xyzs, out_xyz);
  ballq_kernel<<<(B * T * 3 * M) / 4, 256, 0, stream>>>(xyzs, out_xyz, idxbuf);
  mlp_kernel<<<(B * T * M) / 4, 256, 0, stream>>>(xyzs, featT, Wd, Wf, W1, out_xyz, idxbuf,
                                                  out_feats);
}

// Round 2
// 2568.812 us; speedup vs baseline: 1.1486x; 1.1486x over previous
//
#include <hip/hip_runtime.h>

constexpr int B = 4, T = 8, N = 4096, C0 = 64, C1 = 128;
constexpr int M = 1024, KNN = 32;

// ---------------- transpose features (B,T,64,4096) -> featT (B,T,4096,64) ----
__global__ __launch_bounds__(256) void transpose_kernel(const float* __restrict__ f,
                                                        float* __restrict__ ft) {
  __shared__ float tile[64][65];
  int bt = blockIdx.y;                 // 0..31
  int n0 = blockIdx.x * 64;            // n chunk
  const float* src = f + (size_t)bt * C0 * N;
  int tx = threadIdx.x & 63, ty = threadIdx.x >> 6;  // 256 threads
  for (int r = ty; r < 64; r += 4)
    tile[r][tx] = src[(size_t)r * N + n0 + tx];
  __syncthreads();
  float* dst = ft + ((size_t)bt * N + n0) * 64;
  for (int r = ty; r < 64; r += 4)
    dst[(size_t)r * 64 + tx] = tile[tx][r];
}

// ---------------- furthest point sampling: one block (4 waves) per (b,t) ----
// 256 threads, 16 points per lane held in registers. Per iteration:
//  - 3 uniform LDS broadcast reads of the last-picked point
//  - 16 register-resident distance updates (bit-identical arithmetic to ref)
//  - in-wave (val,idx) shfl reduce, 4-slot LDS cross-wave exchange, 1 barrier
__global__ __launch_bounds__(256) void fps_kernel(const float* __restrict__ xyz,
                                                  float* __restrict__ out_xyz) {
  __shared__ float xs[N], ys[N], zs[N];
  __shared__ float rv[2][4];
  __shared__ int ri[2][4];
  int bt = blockIdx.x;
  const float* p = xyz + (size_t)bt * N * 3;
  int tid = threadIdx.x;
  int lane = tid & 63, w = tid >> 6;
  for (int i = tid; i < N; i += 256) {
    xs[i] = p[i * 3 + 0];
    ys[i] = p[i * 3 + 1];
    zs[i] = p[i * 3 + 2];
  }
  __syncthreads();
  float X[16], Y[16], Z[16], D[16];
#pragma unroll
  for (int j = 0; j < 16; ++j) {
    X[j] = xs[tid * 16 + j];
    Y[j] = ys[tid * 16 + j];
    Z[j] = zs[tid * 16 + j];
    D[j] = 1e10f;
  }
  if (tid == 0) {
    out_xyz[(size_t)bt * M * 3 + 0] = xs[0];
    out_xyz[(size_t)bt * M * 3 + 1] = ys[0];
    out_xyz[(size_t)bt * M * 3 + 2] = zs[0];
  }
  int lidx = 0;
  for (int s = 1; s < M; ++s) {
    float lx = xs[lidx], ly = ys[lidx], lz = zs[lidx];
    float bv = -1.0f;
    int bi = 0x7fffffff;
#pragma unroll
    for (int j = 0; j < 16; ++j) {
      float dx = __fsub_rn(X[j], lx);
      float dy = __fsub_rn(Y[j], ly);
      float dz = __fsub_rn(Z[j], lz);
      float d = __fadd_rn(__fadd_rn(__fmul_rn(dx, dx), __fmul_rn(dy, dy)), __fmul_rn(dz, dz));
      float nd = fminf(D[j], d);
      D[j] = nd;
      // j ascending => index ascending; strict > keeps earliest index
      if (nd > bv) { bv = nd; bi = tid * 16 + j; }
    }
    // in-wave (val,idx) reduce, first-occurrence tie-break (smaller idx wins)
#pragma unroll
    for (int off = 1; off < 64; off <<= 1) {
      float ov = __shfl_xor(bv, off, 64);
      int oi = __shfl_xor(bi, off, 64);
      if (ov > bv || (ov == bv && oi < bi)) { bv = ov; bi = oi; }
    }
    int buf = s & 1;
    if (lane == 0) { rv[buf][w] = bv; ri[buf][w] = bi; }
    __syncthreads();
    // every wave resolves the winner redundantly (no divergence, no 2nd barrier:
    // next iteration writes the other buffer)
    float fv = rv[buf][0];
    int fi = ri[buf][0];
#pragma unroll
    for (int q = 1; q < 4; ++q) {
      float ov = rv[buf][q];
      int oi = ri[buf][q];
      if (ov > fv || (ov == fv && oi < fi)) { fv = ov; fi = oi; }
    }
    lidx = fi;
    if (tid == 0) {
      out_xyz[((size_t)(bt * M + s)) * 3 + 0] = xs[lidx];
      out_xyz[((size_t)(bt * M + s)) * 3 + 1] = ys[lidx];
      out_xyz[((size_t)(bt * M + s)) * 3 + 2] = zs[lidx];
    }
  }
}

// ---------------- ball query: one wave per (b,t,di,m) -----------------------
__global__ __launch_bounds__(256) void ballq_kernel(const float* __restrict__ xyz,
                                                    const float* __restrict__ anchors,
                                                    int* __restrict__ idxbuf) {
  const float R2 = 0.04f;
  int w = threadIdx.x >> 6, lane = threadIdx.x & 63;
  int q = blockIdx.x * 4 + w;  // 0..98303  q = (bt*3 + di)*M + m
  int m = q & (M - 1);
  int di = (q >> 10) % 3;
  int bt = q / (M * 3);
  int b = bt >> 3, t = bt & 7;
  int srct = t + di - 1;
  srct = srct < 0 ? 0 : (srct > 7 ? 7 : srct);
  const float* anc = anchors + ((size_t)(bt * M + m)) * 3;
  float ax = anc[0], ay = anc[1], az = anc[2];
  const float* pts = xyz + ((size_t)(b * T + srct)) * N * 3;
  int* outp = idxbuf + (size_t)q * KNN;
  int cnt = 0, first = 0;
  for (int c = 0; c < N / 64 && cnt < KNN; ++c) {
    int pi = c * 64 + lane;
    const float* pp = pts + (size_t)pi * 3;
    float dx = __fsub_rn(ax, pp[0]);
    float dy = __fsub_rn(ay, pp[1]);
    float dz = __fsub_rn(az, pp[2]);
    float d2 = __fadd_rn(__fadd_rn(__fmul_rn(dx, dx), __fmul_rn(dy, dy)), __fmul_rn(dz, dz));
    bool hit = d2 < R2;
    unsigned long long mask = __ballot(hit);
    if (cnt == 0 && mask) first = c * 64 + (int)__builtin_ctzll(mask);
    int prefix = (int)__popcll(mask & ((1ull << lane) - 1ull));
    int slot = cnt + prefix;
    if (hit && slot < KNN) outp[slot] = pi;
    cnt += (int)__popcll(mask);
  }
  int cntK = cnt < KNN ? cnt : KNN;
  int fill = (cnt == 0) ? 0 : first;
  if (lane < KNN && lane >= cntK) outp[lane] = fill;
}

// ---------------- fused grouping + 2-layer MLP + maxpool + temporal sum -----
__global__ __launch_bounds__(256) void mlp_kernel(const float* __restrict__ xyz,
                                                  const float* __restrict__ featT,
                                                  const float* __restrict__ Wd,
                                                  const float* __restrict__ Wf,
                                                  const float* __restrict__ W1,
                                                  const float* __restrict__ anchors,
                                                  const int* __restrict__ idxbuf,
                                                  float* __restrict__ out_feats) {
  __shared__ __align__(16) float hbuf[4][64];
  __shared__ __align__(16) float fstage[4][128];
  int w = threadIdx.x >> 6, lane = threadIdx.x & 63;
  int bt = blockIdx.x >> 8;            // 8192 blocks
  int m0 = (blockIdx.x & 255) * 4;
  int m = m0 + w;
  int b = bt >> 3, t = bt & 7;
  // per-lane weight rows in registers
  float wf[64], w1a[64], w1b[64];
#pragma unroll
  for (int c = 0; c < 64; c += 4) {
    *(float4*)&wf[c] = *(const float4*)&Wf[lane * 64 + c];
    *(float4*)&w1a[c] = *(const float4*)&W1[lane * 64 + c];
    *(float4*)&w1b[c] = *(const float4*)&W1[(lane + 64) * 64 + c];
  }
  float4 wd = *(const float4*)&Wd[lane * 4];
  int aoff = __builtin_amdgcn_readfirstlane(bt * M + m);
  float ax = anchors[(size_t)aoff * 3 + 0];
  float ay = anchors[(size_t)aoff * 3 + 1];
  float az = anchors[(size_t)aoff * 3 + 2];
  float a0 = 0.f, a1 = 0.f;
  for (int di = 0; di < 3; ++di) {
    int srct = t + di - 1;
    srct = srct < 0 ? 0 : (srct > 7 ? 7 : srct);
    const float* pts = xyz + ((size_t)(b * T + srct)) * N * 3;
    const float* ft = featT + ((size_t)(b * T + srct)) * N * 64;
    int ipoff = __builtin_amdgcn_readfirstlane(((bt * 3 + di) * M + m) * KNN);
    const int* ip = idxbuf + ipoff;
    float tval = (float)(di - 1);
    float mx0 = 0.f, mx1 = 0.f;
    for (int k = 0; k < KNN; ++k) {
      int n = __builtin_amdgcn_readfirstlane(ip[k]);
      const float* gp = ft + (size_t)n * 64;   // wave-uniform -> s_load
      const float* pp = pts + (size_t)n * 3;
      float px = pp[0], py = pp[1], pz = pp[2];
      float f0 = 0.f, f1 = 0.f, f2 = 0.f, f3 = 0.f;
#pragma unroll
      for (int c = 0; c < 64; c += 4) {
        f0 = fmaf(gp[c + 0], wf[c + 0], f0);
        f1 = fmaf(gp[c + 1], wf[c + 1], f1);
        f2 = fmaf(gp[c + 2], wf[c + 2], f2);
        f3 = fmaf(gp[c + 3], wf[c + 3], f3);
      }
      float ff = (f0 + f1) + (f2 + f3);
      float dd = fmaf(px - ax, wd.x, fmaf(py - ay, wd.y, fmaf(pz - az, wd.z, tval * wd.w)));
      float h = fmaxf(ff, 0.f) + fmaxf(dd, 0.f);
      hbuf[w][lane] = h;
      float o0a = 0.f, o0b = 0.f, o1a = 0.f, o1b = 0.f;
#pragma unroll
      for (int c = 0; c < 64; c += 4) {
        float4 hv = *(const float4*)&hbuf[w][c];
        o0a = fmaf(hv.x, w1a[c + 0], o0a); o1a = fmaf(hv.x, w1b[c + 0], o1a);
        o0b = fmaf(hv.y, w1a[c + 1], o0b); o1b = fmaf(hv.y, w1b[c + 1], o1b);
        o0a = fmaf(hv.z, w1a[c + 2], o0a); o1a = fmaf(hv.z, w1b[c + 2], o1a);
        o0b = fmaf(hv.w, w1a[c + 3], o0b); o1b = fmaf(hv.w, w1b[c + 3], o1b);
      }
      float o0 = o0a + o0b, o1 = o1a + o1b;
      mx0 = fmaxf(mx0, fmaxf(o0, 0.f));
      mx1 = fmaxf(mx1, fmaxf(o1, 0.f));
    }
    a0 += mx0;
    a1 += mx1;
  }
  fstage[w][lane] = a0;
  fstage[w][lane + 64] = a1;
  __syncthreads();
  if (threadIdx.x < 128) {
    int c1 = threadIdx.x;
    float4 v = make_float4(fstage[0][c1], fstage[1][c1], fstage[2][c1], fstage[3][c1]);
    *(float4*)&out_feats[((size_t)(bt * C1 + c1)) * M + m0] = v;
  }
}

extern "C" void kernel_launch(void* const* d_in, const int* in_sizes, int n_in,
                              void* d_out, int out_size, void* d_ws, size_t ws_size,
                              hipStream_t stream) {
  const float* xyzs = (const float*)d_in[0];
  const float* feats = (const float*)d_in[1];
  const float* Wd = (const float*)d_in[2];
  const float* Wf = (const float*)d_in[3];
  const float* W1 = (const float*)d_in[4];
  float* out_xyz = (float*)d_out;                           // (B,8,M,3)
  float* out_feats = (float*)d_out + (size_t)B * T * M * 3; // (B,8,C1,M)
  char* ws = (char*)d_ws;
  float* featT = (float*)ws;                                // B*T*N*64 f32 = 33.5MB
  int* idxbuf = (int*)(ws + (size_t)B * T * N * 64 * 4);    // B*T*3*M*K i32 = 12.6MB
  transpose_kernel<<<dim3(N / 64, B * T), 256, 0, stream>>>(feats, featT);
  fps_kernel<<<B * T, 256, 0, stream>>>(xyzs, out_xyz);
  ballq_kernel<<<(B * T * 3 * M) / 4, 256, 0, stream>>>(xyzs, out_xyz, idxbuf);
  mlp_kernel<<<(B * T * M) / 4, 256, 0, stream>>>(xyzs, featT, Wd, Wf, W1, out_xyz, idxbuf,
                                                  out_feats);
}